// Round 9
// baseline (275.856 us; speedup 1.0000x reference)
//
#include <hip/hip_runtime.h>
#include <hip/hip_bf16.h>
#include <math.h>

// ---------------------------------------------------------------------------
// GAT x2 + folded (v-proj -> out-proj -> fc) + log_softmax
//   CSR build: bucket-binning (128-node buckets), esrc uint16.
//   gemm1: MFMA bf16 16x16x32, 64x64 tile.
//   gat_agg64_g2: QUAD-layout fused softmax-aggregate: lane = edge*16 + chquad,
//     4 edges/iter, 8B bf16x4 gathers, unroll x2 -> ~12 issue-cyc/edge (2x
//     less than pair layout). Fused gemm2 epilogue w/ 4 independent chains.
//   gat_agg32_fin: 1 node/wave, 8 edges/iter, exp exactly once per
//     (edge,head); fused final (M matvec + log_softmax).
// ---------------------------------------------------------------------------

#define BSHIFT 7
#define BMASK  ((1 << BSHIFT) - 1)
#define MAXNB  512
#define TILE   8192
#define XST    136

typedef __attribute__((ext_vector_type(8))) short short8;
typedef __attribute__((ext_vector_type(4))) float floatx4;

__device__ __forceinline__ unsigned short f2bf(float f) {
    union { float f; unsigned int u; } v; v.f = f;
    unsigned int u = v.u;
    return (unsigned short)((u + 0x7FFFu + ((u >> 16) & 1u)) >> 16);  // RNE
}
__device__ __forceinline__ float bfl2f(unsigned int p) {
    return __uint_as_float(p << 16);
}
__device__ __forceinline__ float bfh2f(unsigned int p) {
    return __uint_as_float(p & 0xFFFF0000u);
}
__device__ __forceinline__ float lrelu(float e) { return fmaxf(e, 0.2f * e); }
__device__ __forceinline__ float elu(float o) {
    return (o > 0.f) ? o : (__expf(o) - 1.f);
}

// ---------------- CSR build (bucket binning) ----------------
__global__ __launch_bounds__(256) void bin_count_kernel(
    const int* __restrict__ ei, int E, int Et, int NB,
    int* __restrict__ bcount) {
    __shared__ int h[MAXNB];
    for (int i = threadIdx.x; i < NB; i += 256) h[i] = 0;
    __syncthreads();
    int tile0 = blockIdx.x * TILE;
    int jend = tile0 + TILE; if (jend > Et) jend = Et;
    for (int j = tile0 + threadIdx.x; j < jend; j += 256) {
        int d = (j < E) ? ei[E + j] : (j - E);
        atomicAdd(&h[d >> BSHIFT], 1);
    }
    __syncthreads();
    for (int i = threadIdx.x; i < NB; i += 256)
        if (h[i]) atomicAdd(&bcount[i], h[i]);
}

__global__ __launch_bounds__(512) void bucket_scan_kernel(
    const int* __restrict__ bcount, int* __restrict__ bbase,
    int* __restrict__ gcur, int NB) {
    __shared__ int s[512];
    int t = threadIdx.x;
    int v = (t < NB) ? bcount[t] : 0;
    s[t] = v;
    __syncthreads();
    for (int off = 1; off < 512; off <<= 1) {
        int u = (t >= off) ? s[t - off] : 0;
        __syncthreads();
        s[t] += u;
        __syncthreads();
    }
    if (t < NB) { int b = s[t] - v; bbase[t] = b; gcur[t] = b; }
}

__global__ __launch_bounds__(256) void bin_scatter_kernel(
    const int* __restrict__ ei, int E, int Et, int NB,
    int* __restrict__ gcur, unsigned int* __restrict__ rec) {
    __shared__ int h[MAXNB];
    __shared__ int cur[MAXNB];
    for (int i = threadIdx.x; i < NB; i += 256) h[i] = 0;
    __syncthreads();
    int tile0 = blockIdx.x * TILE;
    int jend = tile0 + TILE; if (jend > Et) jend = Et;
    for (int j = tile0 + threadIdx.x; j < jend; j += 256) {
        int d = (j < E) ? ei[E + j] : (j - E);
        atomicAdd(&h[d >> BSHIFT], 1);
    }
    __syncthreads();
    for (int i = threadIdx.x; i < NB; i += 256)
        cur[i] = atomicAdd(&gcur[i], h[i]);
    __syncthreads();
    for (int j = tile0 + threadIdx.x; j < jend; j += 256) {
        int srcv, d;
        if (j < E) { srcv = ei[j]; d = ei[E + j]; } else { srcv = j - E; d = j - E; }
        int b = d >> BSHIFT;
        int pos = atomicAdd(&cur[b], 1);
        rec[pos] = (unsigned)srcv | ((unsigned)(d & BMASK) << 16);
    }
}

__global__ __launch_bounds__(256) void csr_finalize_kernel(
    const unsigned int* __restrict__ rec, const int* __restrict__ bcount,
    const int* __restrict__ bbase, int* __restrict__ rowp,
    unsigned short* __restrict__ esrc, int N, int Et) {
    __shared__ int h[128];
    __shared__ int nb[128];
    __shared__ int cur[128];
    int b = blockIdx.x, t = threadIdx.x;
    int base = bbase[b], cnt = bcount[b];
    if (t < 128) h[t] = 0;
    __syncthreads();
    for (int i = t; i < cnt; i += 256)
        atomicAdd(&h[(rec[base + i] >> 16) & 127], 1);
    __syncthreads();
    if (t == 0) {
        int run = base;
        for (int i = 0; i < 128; ++i) { nb[i] = run; run += h[i]; }
    }
    __syncthreads();
    if (t < 128) cur[t] = nb[t];
    int n0 = b << BSHIFT;
    if (t < 128 && n0 + t < N) rowp[n0 + t] = nb[t];
    if (b == 0 && t == 0) rowp[N] = Et;
    __syncthreads();
    for (int i = t; i < cnt; i += 256) {
        unsigned r = rec[base + i];
        int pos = atomicAdd(&cur[(r >> 16) & 127], 1);
        esrc[pos] = (unsigned short)(r & 0xFFFFu);
    }
}

// ---------------- gemm1 via MFMA ----------------
__global__ __launch_bounds__(256) void gemm1_mfma_kernel(
    const float* __restrict__ x, const float* __restrict__ W,
    const float* __restrict__ a_src, const float* __restrict__ a_dst,
    __hip_bfloat16* __restrict__ h, float* __restrict__ als,
    float* __restrict__ ald, int N) {
    __shared__ __align__(16) unsigned short xs[64 * XST];
    __shared__ __align__(16) unsigned short wt[64 * XST];
    int t = threadIdx.x;
    int nb = blockIdx.x * 64;
#pragma unroll
    for (int r = 0; r < 8; ++r) {
        int p = t + 256 * r;
        int row = p >> 5;
        int c4  = p & 31;
        int n = nb + row;
        float4 v = (n < N) ? ((const float4*)x)[(size_t)n * 32 + c4]
                           : make_float4(0.f, 0.f, 0.f, 0.f);
        unsigned short* dst = &xs[row * XST + c4 * 4];
        dst[0] = f2bf(v.x); dst[1] = f2bf(v.y);
        dst[2] = f2bf(v.z); dst[3] = f2bf(v.w);
    }
    {
        int n = t & 63, kg = t >> 6;
#pragma unroll
        for (int c = 0; c < 4; ++c) {
            int k0 = kg * 32 + c * 8;
            unsigned short* dst = &wt[n * XST + k0];
#pragma unroll
            for (int j = 0; j < 8; ++j)
                dst[j] = f2bf(W[(k0 + j) * 64 + n]);
        }
    }
    __syncthreads();
    int wave = t >> 6, lane = t & 63;
    int m16 = lane & 15, quad = lane >> 4;
    floatx4 acc[4];
#pragma unroll
    for (int i = 0; i < 4; ++i) acc[i] = (floatx4){0.f, 0.f, 0.f, 0.f};
#pragma unroll
    for (int k = 0; k < 4; ++k) {
        int koff = k * 32 + quad * 8;
        short8 afrag = *(const short8*)&xs[(wave * 16 + m16) * XST + koff];
#pragma unroll
        for (int nt = 0; nt < 4; ++nt) {
            short8 bfrag = *(const short8*)&wt[(nt * 16 + m16) * XST + koff];
            acc[nt] = __builtin_amdgcn_mfma_f32_16x16x32_bf16(afrag, bfrag, acc[nt], 0, 0, 0);
        }
    }
    __syncthreads();
    float* hs = (float*)xs;                // [64][65]
#pragma unroll
    for (int nt = 0; nt < 4; ++nt)
#pragma unroll
        for (int r = 0; r < 4; ++r)
            hs[(wave * 16 + quad * 4 + r) * 65 + nt * 16 + m16] = acc[nt][r];
    __syncthreads();
    float asv = a_src[lane], adv = a_dst[lane];
    for (int itn = 0; itn < 16; ++itn) {
        int nl = wave * 16 + itn;
        int n = nb + nl;
        if (n >= N) break;
        float v = hs[nl * 65 + lane];
        h[(size_t)n * 64 + lane] = __float2bfloat16(v);
        float ps = v * asv, pd = v * adv;
        ps += __shfl_xor(ps, 1); ps += __shfl_xor(ps, 2); ps += __shfl_xor(ps, 4);
        pd += __shfl_xor(pd, 1); pd += __shfl_xor(pd, 2); pd += __shfl_xor(pd, 4);
        if ((lane & 7) == 0) {
            als[n * 8 + (lane >> 3)] = ps;
            ald[n * 8 + (lane >> 3)] = pd;
        }
    }
}

// ---------------- agg layer 1 (quad layout) + fused gemm2 ----------------
// One wave per node. lane = e*16 + c: e = edge slot (4/iter), c = channel
// quad (ch 4c..4c+3, head c>>1). 8B bf16x4 gathers; unroll x2 (8 edges).
// xor-reduce leaves o + d broadcast in all lanes -> cheap epilogue.
__global__ __launch_bounds__(256) void gat_agg64_g2_kernel(
    const int* __restrict__ rowp, const unsigned short* __restrict__ esrc,
    const __hip_bfloat16* __restrict__ feat, const float* __restrict__ als,
    const float* __restrict__ ald_arr, const float* __restrict__ bias,
    const float* __restrict__ W2, const float* __restrict__ a2s,
    const float* __restrict__ a2d,
    __hip_bfloat16* __restrict__ h2out, float* __restrict__ als2,
    float* __restrict__ ald2, int N) {
    __shared__ float W2s[64 * 32];
    int t = threadIdx.x;
    for (int i = t; i < 2048; i += 256) W2s[i] = W2[i];
    __syncthreads();
    const int lane = t & 63;
    const int e = lane >> 4;             // edge slot 0..3
    const int c = lane & 15;             // channel quad
    const int hd = c >> 1;               // head
    int n = blockIdx.x * 4 + (t >> 6);
    if (n >= N) return;
    float aldv = ald_arr[n * 8 + hd];
    int beg = rowp[n], end = rowp[n + 1];
    float p0 = 0.f, p1 = 0.f, p2 = 0.f, p3 = 0.f;
    float q0 = 0.f, q1 = 0.f, q2 = 0.f, q3 = 0.f;
    float dA = 0.f, dB = 0.f;
    const uint2* fp = (const uint2*)feat;    // 16 granules (8B) per row
    int i = beg;
    for (; i + 8 <= end; i += 8) {
        int sA = esrc[i + e];
        int sB = esrc[i + 4 + e];
        float eA = als[sA * 8 + hd] + aldv;
        float eB = als[sB * 8 + hd] + aldv;
        uint2 gA = fp[sA * 16 + c];
        uint2 gB = fp[sB * 16 + c];
        float wA = __expf(lrelu(eA));
        float wB = __expf(lrelu(eB));
        dA += wA; dB += wB;
        p0 += wA * bfl2f(gA.x); p1 += wA * bfh2f(gA.x);
        p2 += wA * bfl2f(gA.y); p3 += wA * bfh2f(gA.y);
        q0 += wB * bfl2f(gB.x); q1 += wB * bfh2f(gB.x);
        q2 += wB * bfl2f(gB.y); q3 += wB * bfh2f(gB.y);
    }
    for (; i < end; i += 4) {            // masked tail, 4 at a time
        int rem = end - i;
        int ee = (e < rem) ? e : rem - 1;
        int s = esrc[i + ee];
        float ev = als[s * 8 + hd] + aldv;
        uint2 g = fp[s * 16 + c];
        float w = (e < rem) ? __expf(lrelu(ev)) : 0.f;
        dA += w;
        p0 += w * bfl2f(g.x); p1 += w * bfh2f(g.x);
        p2 += w * bfl2f(g.y); p3 += w * bfh2f(g.y);
    }
    float d = dA + dB;
    p0 += q0; p1 += q1; p2 += q2; p3 += q3;
    d  += __shfl_xor(d, 16);  d  += __shfl_xor(d, 32);
    p0 += __shfl_xor(p0, 16); p0 += __shfl_xor(p0, 32);
    p1 += __shfl_xor(p1, 16); p1 += __shfl_xor(p1, 32);
    p2 += __shfl_xor(p2, 16); p2 += __shfl_xor(p2, 32);
    p3 += __shfl_xor(p3, 16); p3 += __shfl_xor(p3, 32);
    float inv = 1.f / (d + 1e-16f);
    float4 bv = ((const float4*)bias)[c];
    float o0 = elu(p0 * inv + bv.x);
    float o1 = elu(p1 * inv + bv.y);
    float o2 = elu(p2 * inv + bv.z);
    float o3 = elu(p3 * inv + bv.w);
    // fused gemm2: h2[l] = sum_k o[k]*W2[k][l]; split-k over wave halves,
    // 4 independent accumulator chains; o broadcast in all lanes (lane&15=c).
    const int l = lane & 31, khalf = lane >> 5;
    float a0 = 0.f, a1 = 0.f, a2 = 0.f, a3 = 0.f;
#pragma unroll
    for (int kk = 0; kk < 32; kk += 4) {
        int k = khalf * 32 + kk;
        int sc = k >> 2;                 // source lane (0..15)
        a0 += __shfl(o0, sc) * W2s[(k + 0) * 32 + l];
        a1 += __shfl(o1, sc) * W2s[(k + 1) * 32 + l];
        a2 += __shfl(o2, sc) * W2s[(k + 2) * 32 + l];
        a3 += __shfl(o3, sc) * W2s[(k + 3) * 32 + l];
    }
    float acc = (a0 + a1) + (a2 + a3);
    acc += __shfl_xor(acc, 32);
    float ps = acc * a2s[l], pd = acc * a2d[l];
    ps += __shfl_xor(ps, 1); ps += __shfl_xor(ps, 2);
    pd += __shfl_xor(pd, 1); pd += __shfl_xor(pd, 2);
    if (lane < 32) {
        h2out[(size_t)n * 32 + l] = __float2bfloat16(acc);
        if ((l & 3) == 0) {
            als2[n * 8 + (l >> 2)] = ps;
            ald2[n * 8 + (l >> 2)] = pd;
        }
    }
}

// ---------------- agg layer 2 (octo layout) + fused final ----------------
// One wave per node. lane = e*8 + c: e = edge slot (8/iter), c = head
// (ch 4c..4c+3) -> exp exactly once per (edge,head).
__global__ __launch_bounds__(256) void gat_agg32_fin_kernel(
    const int* __restrict__ rowp, const unsigned short* __restrict__ esrc,
    const __hip_bfloat16* __restrict__ feat, const float* __restrict__ als,
    const float* __restrict__ ald_arr, const float* __restrict__ bias,
    const float* __restrict__ M, const float* __restrict__ bf,
    float* __restrict__ out, int N) {
    __shared__ float Ms[16 * 33];
    __shared__ float bfs[16];
    int t = threadIdx.x;
    for (int i = t; i < 512; i += 256) Ms[(i >> 5) * 33 + (i & 31)] = M[i];
    if (t < 16) bfs[t] = bf[t];
    __syncthreads();
    const int lane = t & 63;
    const int e = lane >> 3;             // edge slot 0..7
    const int c = lane & 7;              // head, channels 4c..4c+3
    int n = blockIdx.x * 4 + (t >> 6);
    if (n >= N) return;
    float aldv = ald_arr[n * 8 + c];
    int beg = rowp[n], end = rowp[n + 1];
    float p0 = 0.f, p1 = 0.f, p2 = 0.f, p3 = 0.f, d = 0.f;
    const uint2* fp = (const uint2*)feat;    // 8 granules per row
    int i = beg;
    for (; i + 8 <= end; i += 8) {
        int s = esrc[i + e];
        float ev = als[s * 8 + c] + aldv;
        uint2 g = fp[s * 8 + c];
        float w = __expf(lrelu(ev));
        d += w;
        p0 += w * bfl2f(g.x); p1 += w * bfh2f(g.x);
        p2 += w * bfl2f(g.y); p3 += w * bfh2f(g.y);
    }
    if (i < end) {                       // masked tail (<=7 edges)
        int rem = end - i;
        int ee = (e < rem) ? e : rem - 1;
        int s = esrc[i + ee];
        float ev = als[s * 8 + c] + aldv;
        uint2 g = fp[s * 8 + c];
        float w = (e < rem) ? __expf(lrelu(ev)) : 0.f;
        d += w;
        p0 += w * bfl2f(g.x); p1 += w * bfh2f(g.x);
        p2 += w * bfl2f(g.y); p3 += w * bfh2f(g.y);
    }
    d  += __shfl_xor(d, 8);  d  += __shfl_xor(d, 16);  d  += __shfl_xor(d, 32);
    p0 += __shfl_xor(p0, 8); p0 += __shfl_xor(p0, 16); p0 += __shfl_xor(p0, 32);
    p1 += __shfl_xor(p1, 8); p1 += __shfl_xor(p1, 16); p1 += __shfl_xor(p1, 32);
    p2 += __shfl_xor(p2, 8); p2 += __shfl_xor(p2, 16); p2 += __shfl_xor(p2, 32);
    p3 += __shfl_xor(p3, 8); p3 += __shfl_xor(p3, 16); p3 += __shfl_xor(p3, 32);
    float inv = 1.f / (d + 1e-16f);
    float4 bv = ((const float4*)bias)[c];
    float o0 = elu(p0 * inv + bv.x);
    float o1 = elu(p1 * inv + bv.y);
    float o2 = elu(p2 * inv + bv.z);
    float o3 = elu(p3 * inv + bv.w);
    // fused final: logits[j] = sum_k M[j][k]*o[k] + bf[j]; split-k over 4
    // sections (lane>>4), o broadcast in all lanes (lane&7 = c).
    const int j = lane & 15, ksec = lane >> 4;
    float a0 = 0.f, a1 = 0.f, a2 = 0.f, a3 = 0.f;
#pragma unroll
    for (int kk = 0; kk < 8; kk += 4) {
        int k = ksec * 8 + kk;
        int sc = k >> 2;                 // source lane (0..7)
        a0 += __shfl(o0, sc) * Ms[j * 33 + k + 0];
        a1 += __shfl(o1, sc) * Ms[j * 33 + k + 1];
        a2 += __shfl(o2, sc) * Ms[j * 33 + k + 2];
        a3 += __shfl(o3, sc) * Ms[j * 33 + k + 3];
    }
    float part = (a0 + a1) + (a2 + a3);
    part += __shfl_xor(part, 16);
    part += __shfl_xor(part, 32);
    float logit = part + bfs[j];
    float mx = logit;
    mx = fmaxf(mx, __shfl_xor(mx, 1));
    mx = fmaxf(mx, __shfl_xor(mx, 2));
    mx = fmaxf(mx, __shfl_xor(mx, 4));
    mx = fmaxf(mx, __shfl_xor(mx, 8));
    float ex = __expf(logit - mx);
    float se = ex;
    se += __shfl_xor(se, 1);
    se += __shfl_xor(se, 2);
    se += __shfl_xor(se, 4);
    se += __shfl_xor(se, 8);
    float res = logit - (mx + __logf(se));
    if (lane < 16) out[(size_t)n * 16 + j] = res;
}

// ---------------- fold ----------------
__global__ __launch_bounds__(256) void fold_kernel(
    const float* __restrict__ in_proj_w, const float* __restrict__ in_proj_b,
    const float* __restrict__ out_proj_w, const float* __restrict__ out_proj_b,
    const float* __restrict__ fc_w, const float* __restrict__ fc_b,
    float* __restrict__ M, float* __restrict__ bf) {
    __shared__ float Wvo[32 * 32];
    __shared__ float bvo[32];
    const float* Wv = in_proj_w + 64 * 32;
    const float* bv = in_proj_b + 64;
    int t = threadIdx.x;
    for (int idx = t; idx < 1024; idx += 256) {
        int i = idx >> 5, j = idx & 31;
        float s = 0.f;
        for (int k = 0; k < 32; ++k) s += out_proj_w[i * 32 + k] * Wv[k * 32 + j];
        Wvo[idx] = s;
    }
    if (t < 32) {
        float s = 0.f;
        for (int k = 0; k < 32; ++k) s += out_proj_w[t * 32 + k] * bv[k];
        bvo[t] = s + out_proj_b[t];
    }
    __syncthreads();
    for (int idx = t; idx < 16 * 32; idx += 256) {
        int c = idx >> 5, j = idx & 31;
        float s = 0.f;
        for (int i = 0; i < 32; ++i) s += fc_w[c * 32 + i] * Wvo[i * 32 + j];
        M[idx] = s;
    }
    if (t < 16) {
        float s = 0.f;
        for (int i = 0; i < 32; ++i) s += fc_w[t * 32 + i] * bvo[i];
        bf[t] = s + fc_b[t];
    }
}

extern "C" void kernel_launch(void* const* d_in, const int* in_sizes, int n_in,
                              void* d_out, int out_size, void* d_ws, size_t ws_size,
                              hipStream_t stream) {
    const float* x   = (const float*)d_in[0];
    const int*   ei  = (const int*)d_in[1];
    const float* W1  = (const float*)d_in[2];
    const float* a1s = (const float*)d_in[3];
    const float* a1d = (const float*)d_in[4];
    const float* b1  = (const float*)d_in[5];
    const float* W2  = (const float*)d_in[6];
    const float* a2s = (const float*)d_in[7];
    const float* a2d = (const float*)d_in[8];
    const float* b2  = (const float*)d_in[9];
    const float* ipw = (const float*)d_in[10];
    const float* ipb = (const float*)d_in[11];
    const float* opw = (const float*)d_in[12];
    const float* opb = (const float*)d_in[13];
    const float* fcw = (const float*)d_in[14];
    const float* fcb = (const float*)d_in[15];
    float* out = (float*)d_out;

    int N = in_sizes[0] / 128;
    int E = in_sizes[1] / 2;
    int Et = E + N;
    int NB = (N + BMASK) >> BSHIFT;
    int NTILES = (Et + TILE - 1) / TILE;

    char* ws = (char*)d_ws;
    size_t off = 0;
    auto alloc = [&](size_t bytes) -> void* {
        void* p = ws + off;
        off += bytes;
        off = (off + 255) & ~(size_t)255;
        return p;
    };
    int*   bcount = (int*)alloc(MAXNB * 4);
    int*   bbase  = (int*)alloc(MAXNB * 4);
    int*   gcur   = (int*)alloc(MAXNB * 4);
    unsigned int*   rec  = (unsigned int*)alloc((size_t)Et * 4);
    int*   rowp   = (int*)alloc((size_t)(N + 1) * 4);
    unsigned short* esrc = (unsigned short*)alloc((size_t)Et * 2);
    __hip_bfloat16* h1 = (__hip_bfloat16*)alloc((size_t)N * 64 * 2);
    float* al1s  = (float*)alloc((size_t)N * 8 * 4);
    float* al1d  = (float*)alloc((size_t)N * 8 * 4);
    __hip_bfloat16* h2 = (__hip_bfloat16*)alloc((size_t)N * 32 * 2);
    float* al2s  = (float*)alloc((size_t)N * 8 * 4);
    float* al2d  = (float*)alloc((size_t)N * 8 * 4);
    float* Mf    = (float*)alloc(512 * 4);
    float* bff   = (float*)alloc(16 * 4);
    (void)ws_size; (void)n_in; (void)out_size;

    hipMemsetAsync(bcount, 0, MAXNB * 4, stream);
    bin_count_kernel<<<NTILES, 256, 0, stream>>>(ei, E, Et, NB, bcount);
    bucket_scan_kernel<<<1, 512, 0, stream>>>(bcount, bbase, gcur, NB);
    bin_scatter_kernel<<<NTILES, 256, 0, stream>>>(ei, E, Et, NB, gcur, rec);
    csr_finalize_kernel<<<NB, 256, 0, stream>>>(rec, bcount, bbase, rowp, esrc, N, Et);

    gemm1_mfma_kernel<<<(N + 63) / 64, 256, 0, stream>>>(x, W1, a1s, a1d, h1, al1s, al1d, N);
    fold_kernel<<<1, 256, 0, stream>>>(ipw, ipb, opw, opb, fcw, fcb, Mf, bff);
    gat_agg64_g2_kernel<<<(N + 3) / 4, 256, 0, stream>>>(
        rowp, esrc, h1, al1s, al1d, b1, W2, a2s, a2d, h2, al2s, al2d, N);
    gat_agg32_fin_kernel<<<(N + 3) / 4, 256, 0, stream>>>(
        rowp, esrc, h2, al2s, al2d, b2, Mf, bff, out, N);
}

// Round 10
// 261.869 us; speedup vs baseline: 1.0534x; 1.0534x over previous
//
#include <hip/hip_runtime.h>
#include <hip/hip_bf16.h>
#include <math.h>

// ---------------------------------------------------------------------------
// GAT x2 + folded (v-proj -> out-proj -> fc) + log_softmax
//   CSR build: bucket-binning (128-node buckets), esrc uint16.
//   gemm1: MFMA bf16 16x16x32, 64x64 tile.
//   gat_agg64_g2: quad layout UNROLL x4 (16 edges/iter, 4 independent gather
//     streams/lane) + esrc software prefetch. DS-light fused gemm2 epilogue:
//     o staged to LDS once, W2 transposed -> b128 reads, no bpermutes.
//   gat_agg32_fin: octo layout unroll x2 + prefetch; redundant-per-group
//     final matvec from LDS (no split-k shuffles) + log_softmax.
//   Lessons encoded: independent gather streams >> fewer VALU instrs (R6/R8);
//   __shfl = DS-pipe op, avoid in per-node epilogues (R7).
// ---------------------------------------------------------------------------

#define BSHIFT 7
#define BMASK  ((1 << BSHIFT) - 1)
#define MAXNB  512
#define TILE   8192
#define XST    136

typedef __attribute__((ext_vector_type(8))) short short8;
typedef __attribute__((ext_vector_type(4))) float floatx4;

__device__ __forceinline__ unsigned short f2bf(float f) {
    union { float f; unsigned int u; } v; v.f = f;
    unsigned int u = v.u;
    return (unsigned short)((u + 0x7FFFu + ((u >> 16) & 1u)) >> 16);  // RNE
}
__device__ __forceinline__ float bfl2f(unsigned int p) {
    return __uint_as_float(p << 16);
}
__device__ __forceinline__ float bfh2f(unsigned int p) {
    return __uint_as_float(p & 0xFFFF0000u);
}
__device__ __forceinline__ float lrelu(float e) { return fmaxf(e, 0.2f * e); }
__device__ __forceinline__ float elu(float o) {
    return (o > 0.f) ? o : (__expf(o) - 1.f);
}

// ---------------- CSR build (bucket binning) ----------------
__global__ __launch_bounds__(256) void bin_count_kernel(
    const int* __restrict__ ei, int E, int Et, int NB,
    int* __restrict__ bcount) {
    __shared__ int h[MAXNB];
    for (int i = threadIdx.x; i < NB; i += 256) h[i] = 0;
    __syncthreads();
    int tile0 = blockIdx.x * TILE;
    int jend = tile0 + TILE; if (jend > Et) jend = Et;
    for (int j = tile0 + threadIdx.x; j < jend; j += 256) {
        int d = (j < E) ? ei[E + j] : (j - E);
        atomicAdd(&h[d >> BSHIFT], 1);
    }
    __syncthreads();
    for (int i = threadIdx.x; i < NB; i += 256)
        if (h[i]) atomicAdd(&bcount[i], h[i]);
}

__global__ __launch_bounds__(512) void bucket_scan_kernel(
    const int* __restrict__ bcount, int* __restrict__ bbase,
    int* __restrict__ gcur, int NB) {
    __shared__ int s[512];
    int t = threadIdx.x;
    int v = (t < NB) ? bcount[t] : 0;
    s[t] = v;
    __syncthreads();
    for (int off = 1; off < 512; off <<= 1) {
        int u = (t >= off) ? s[t - off] : 0;
        __syncthreads();
        s[t] += u;
        __syncthreads();
    }
    if (t < NB) { int b = s[t] - v; bbase[t] = b; gcur[t] = b; }
}

__global__ __launch_bounds__(256) void bin_scatter_kernel(
    const int* __restrict__ ei, int E, int Et, int NB,
    int* __restrict__ gcur, unsigned int* __restrict__ rec) {
    __shared__ int h[MAXNB];
    __shared__ int cur[MAXNB];
    for (int i = threadIdx.x; i < NB; i += 256) h[i] = 0;
    __syncthreads();
    int tile0 = blockIdx.x * TILE;
    int jend = tile0 + TILE; if (jend > Et) jend = Et;
    for (int j = tile0 + threadIdx.x; j < jend; j += 256) {
        int d = (j < E) ? ei[E + j] : (j - E);
        atomicAdd(&h[d >> BSHIFT], 1);
    }
    __syncthreads();
    for (int i = threadIdx.x; i < NB; i += 256)
        cur[i] = atomicAdd(&gcur[i], h[i]);
    __syncthreads();
    for (int j = tile0 + threadIdx.x; j < jend; j += 256) {
        int srcv, d;
        if (j < E) { srcv = ei[j]; d = ei[E + j]; } else { srcv = j - E; d = j - E; }
        int b = d >> BSHIFT;
        int pos = atomicAdd(&cur[b], 1);
        rec[pos] = (unsigned)srcv | ((unsigned)(d & BMASK) << 16);
    }
}

__global__ __launch_bounds__(256) void csr_finalize_kernel(
    const unsigned int* __restrict__ rec, const int* __restrict__ bcount,
    const int* __restrict__ bbase, int* __restrict__ rowp,
    unsigned short* __restrict__ esrc, int N, int Et) {
    __shared__ int h[128];
    __shared__ int nb[128];
    __shared__ int cur[128];
    int b = blockIdx.x, t = threadIdx.x;
    int base = bbase[b], cnt = bcount[b];
    if (t < 128) h[t] = 0;
    __syncthreads();
    for (int i = t; i < cnt; i += 256)
        atomicAdd(&h[(rec[base + i] >> 16) & 127], 1);
    __syncthreads();
    if (t == 0) {
        int run = base;
        for (int i = 0; i < 128; ++i) { nb[i] = run; run += h[i]; }
    }
    __syncthreads();
    if (t < 128) cur[t] = nb[t];
    int n0 = b << BSHIFT;
    if (t < 128 && n0 + t < N) rowp[n0 + t] = nb[t];
    if (b == 0 && t == 0) rowp[N] = Et;
    __syncthreads();
    for (int i = t; i < cnt; i += 256) {
        unsigned r = rec[base + i];
        int pos = atomicAdd(&cur[(r >> 16) & 127], 1);
        esrc[pos] = (unsigned short)(r & 0xFFFFu);
    }
}

// ---------------- gemm1 via MFMA ----------------
__global__ __launch_bounds__(256) void gemm1_mfma_kernel(
    const float* __restrict__ x, const float* __restrict__ W,
    const float* __restrict__ a_src, const float* __restrict__ a_dst,
    __hip_bfloat16* __restrict__ h, float* __restrict__ als,
    float* __restrict__ ald, int N) {
    __shared__ __align__(16) unsigned short xs[64 * XST];
    __shared__ __align__(16) unsigned short wt[64 * XST];
    int t = threadIdx.x;
    int nb = blockIdx.x * 64;
#pragma unroll
    for (int r = 0; r < 8; ++r) {
        int p = t + 256 * r;
        int row = p >> 5;
        int c4  = p & 31;
        int n = nb + row;
        float4 v = (n < N) ? ((const float4*)x)[(size_t)n * 32 + c4]
                           : make_float4(0.f, 0.f, 0.f, 0.f);
        unsigned short* dst = &xs[row * XST + c4 * 4];
        dst[0] = f2bf(v.x); dst[1] = f2bf(v.y);
        dst[2] = f2bf(v.z); dst[3] = f2bf(v.w);
    }
    {
        int n = t & 63, kg = t >> 6;
#pragma unroll
        for (int c = 0; c < 4; ++c) {
            int k0 = kg * 32 + c * 8;
            unsigned short* dst = &wt[n * XST + k0];
#pragma unroll
            for (int j = 0; j < 8; ++j)
                dst[j] = f2bf(W[(k0 + j) * 64 + n]);
        }
    }
    __syncthreads();
    int wave = t >> 6, lane = t & 63;
    int m16 = lane & 15, quad = lane >> 4;
    floatx4 acc[4];
#pragma unroll
    for (int i = 0; i < 4; ++i) acc[i] = (floatx4){0.f, 0.f, 0.f, 0.f};
#pragma unroll
    for (int k = 0; k < 4; ++k) {
        int koff = k * 32 + quad * 8;
        short8 afrag = *(const short8*)&xs[(wave * 16 + m16) * XST + koff];
#pragma unroll
        for (int nt = 0; nt < 4; ++nt) {
            short8 bfrag = *(const short8*)&wt[(nt * 16 + m16) * XST + koff];
            acc[nt] = __builtin_amdgcn_mfma_f32_16x16x32_bf16(afrag, bfrag, acc[nt], 0, 0, 0);
        }
    }
    __syncthreads();
    float* hs = (float*)xs;                // [64][65]
#pragma unroll
    for (int nt = 0; nt < 4; ++nt)
#pragma unroll
        for (int r = 0; r < 4; ++r)
            hs[(wave * 16 + quad * 4 + r) * 65 + nt * 16 + m16] = acc[nt][r];
    __syncthreads();
    float asv = a_src[lane], adv = a_dst[lane];
    for (int itn = 0; itn < 16; ++itn) {
        int nl = wave * 16 + itn;
        int n = nb + nl;
        if (n >= N) break;
        float v = hs[nl * 65 + lane];
        h[(size_t)n * 64 + lane] = __float2bfloat16(v);
        float ps = v * asv, pd = v * adv;
        ps += __shfl_xor(ps, 1); ps += __shfl_xor(ps, 2); ps += __shfl_xor(ps, 4);
        pd += __shfl_xor(pd, 1); pd += __shfl_xor(pd, 2); pd += __shfl_xor(pd, 4);
        if ((lane & 7) == 0) {
            als[n * 8 + (lane >> 3)] = ps;
            ald[n * 8 + (lane >> 3)] = pd;
        }
    }
}

// ---------------- agg layer 1 (quad x4 + prefetch) + fused gemm2 ----------
// One wave per node. lane = e*16 + c: e = edge slot (0..3), c = channel quad
// (ch 4c..4c+3, head c>>1). 16 edges/iter = 4 independent streams/lane;
// next iteration's esrc prefetched. Epilogue: o -> LDS once; gemm2 reads
// o (broadcast) + transposed W2 as b128 -- no bpermutes.
__global__ __launch_bounds__(256) void gat_agg64_g2_kernel(
    const int* __restrict__ rowp, const unsigned short* __restrict__ esrc,
    const __hip_bfloat16* __restrict__ feat, const float* __restrict__ als,
    const float* __restrict__ ald_arr, const float* __restrict__ bias,
    const float* __restrict__ W2, const float* __restrict__ a2s,
    const float* __restrict__ a2d,
    __hip_bfloat16* __restrict__ h2out, float* __restrict__ als2,
    float* __restrict__ ald2, int N) {
    __shared__ __align__(16) float W2t[32 * 68];   // W2t[l][k], stride 68
    __shared__ __align__(16) float oL[4][64];
    int t = threadIdx.x;
    for (int idx = t; idx < 2048; idx += 256) {
        int k = idx >> 5, l = idx & 31;
        W2t[l * 68 + k] = W2[idx];
    }
    __syncthreads();
    const int lane = t & 63;
    const int wv = t >> 6;
    const int e = lane >> 4;             // edge slot 0..3
    const int c = lane & 15;             // channel quad
    const int hd = c >> 1;               // head
    int n = blockIdx.x * 4 + wv;
    if (n >= N) return;
    float aldv = ald_arr[n * 8 + hd];
    int beg = rowp[n], end = rowp[n + 1];
    float dA = 0.f, dB = 0.f;
    float p00 = 0.f, p01 = 0.f, p02 = 0.f, p03 = 0.f;
    float p10 = 0.f, p11 = 0.f, p12 = 0.f, p13 = 0.f;
    float p20 = 0.f, p21 = 0.f, p22 = 0.f, p23 = 0.f;
    float p30 = 0.f, p31 = 0.f, p32 = 0.f, p33 = 0.f;
    const uint2* fp = (const uint2*)feat;    // 16 8B-granules per row
    int i = beg;
    int s0, s1, s2, s3;
    bool has = (i + 16 <= end);
    if (has) {
        s0 = esrc[i + e]; s1 = esrc[i + 4 + e];
        s2 = esrc[i + 8 + e]; s3 = esrc[i + 12 + e];
    }
    while (has) {
        int t0 = s0, t1 = s1, t2 = s2, t3 = s3;
        i += 16;
        has = (i + 16 <= end);
        if (has) {                        // prefetch next group
            s0 = esrc[i + e]; s1 = esrc[i + 4 + e];
            s2 = esrc[i + 8 + e]; s3 = esrc[i + 12 + e];
        }
        float e0 = als[t0 * 8 + hd] + aldv;
        float e1 = als[t1 * 8 + hd] + aldv;
        float e2 = als[t2 * 8 + hd] + aldv;
        float e3 = als[t3 * 8 + hd] + aldv;
        uint2 g0 = fp[t0 * 16 + c];
        uint2 g1 = fp[t1 * 16 + c];
        uint2 g2 = fp[t2 * 16 + c];
        uint2 g3 = fp[t3 * 16 + c];
        float w0 = __expf(lrelu(e0));
        float w1 = __expf(lrelu(e1));
        float w2 = __expf(lrelu(e2));
        float w3 = __expf(lrelu(e3));
        dA += w0; dB += w1; dA += w2; dB += w3;
        p00 += w0 * bfl2f(g0.x); p01 += w0 * bfh2f(g0.x);
        p02 += w0 * bfl2f(g0.y); p03 += w0 * bfh2f(g0.y);
        p10 += w1 * bfl2f(g1.x); p11 += w1 * bfh2f(g1.x);
        p12 += w1 * bfl2f(g1.y); p13 += w1 * bfh2f(g1.y);
        p20 += w2 * bfl2f(g2.x); p21 += w2 * bfh2f(g2.x);
        p22 += w2 * bfl2f(g2.y); p23 += w2 * bfh2f(g2.y);
        p30 += w3 * bfl2f(g3.x); p31 += w3 * bfh2f(g3.x);
        p32 += w3 * bfl2f(g3.y); p33 += w3 * bfh2f(g3.y);
    }
    for (; i < end; i += 4) {            // masked tail, 4 at a time
        int rem = end - i;
        int ee = (e < rem) ? e : rem - 1;
        int s = esrc[i + ee];
        float ev = als[s * 8 + hd] + aldv;
        uint2 g = fp[s * 16 + c];
        float w = (e < rem) ? __expf(lrelu(ev)) : 0.f;
        dA += w;
        p00 += w * bfl2f(g.x); p01 += w * bfh2f(g.x);
        p02 += w * bfl2f(g.y); p03 += w * bfh2f(g.y);
    }
    float d = dA + dB;
    float P0 = (p00 + p10) + (p20 + p30);
    float P1 = (p01 + p11) + (p21 + p31);
    float P2 = (p02 + p12) + (p22 + p32);
    float P3 = (p03 + p13) + (p23 + p33);
    d  += __shfl_xor(d, 16);  d  += __shfl_xor(d, 32);
    P0 += __shfl_xor(P0, 16); P0 += __shfl_xor(P0, 32);
    P1 += __shfl_xor(P1, 16); P1 += __shfl_xor(P1, 32);
    P2 += __shfl_xor(P2, 16); P2 += __shfl_xor(P2, 32);
    P3 += __shfl_xor(P3, 16); P3 += __shfl_xor(P3, 32);
    float inv = 1.f / (d + 1e-16f);
    float4 bv = ((const float4*)bias)[c];
    float o0 = elu(P0 * inv + bv.x);
    float o1 = elu(P1 * inv + bv.y);
    float o2 = elu(P2 * inv + bv.z);
    float o3 = elu(P3 * inv + bv.w);
    // stage o (64 floats) to LDS once; all lanes hold replicas (lane&15 = c)
    if (lane < 16) *(float4*)&oL[wv][c * 4] = make_float4(o0, o1, o2, o3);
    // gemm2: h2[l] = sum_k o[k]*W2[k][l]; split-k over wave halves; b128 LDS
    const int l = lane & 31, kh = lane >> 5;
    const float* orow = &oL[wv][kh * 32];
    const float* wrow = &W2t[l * 68 + kh * 32];
    float a0 = 0.f, a1 = 0.f, a2 = 0.f, a3 = 0.f;
#pragma unroll
    for (int g = 0; g < 8; ++g) {
        float4 ov = *(const float4*)&orow[g * 4];
        float4 wv4 = *(const float4*)&wrow[g * 4];
        a0 += ov.x * wv4.x; a1 += ov.y * wv4.y;
        a2 += ov.z * wv4.z; a3 += ov.w * wv4.w;
    }
    float acc = (a0 + a1) + (a2 + a3);
    acc += __shfl_xor(acc, 32);
    float ps = acc * a2s[l], pd = acc * a2d[l];
    ps += __shfl_xor(ps, 1); ps += __shfl_xor(ps, 2);
    pd += __shfl_xor(pd, 1); pd += __shfl_xor(pd, 2);
    if (lane < 32) {
        h2out[(size_t)n * 32 + l] = __float2bfloat16(acc);
        if ((l & 3) == 0) {
            als2[n * 8 + (l >> 2)] = ps;
            ald2[n * 8 + (l >> 2)] = pd;
        }
    }
}

// ---------------- agg layer 2 (octo x2 + prefetch) + fused final ----------
// One wave per node. lane = e*8 + c: e = edge slot (0..7), c = head
// (ch 4c..4c+3). 16 edges/iter, esrc prefetched. Final matvec computed
// redundantly per 16-lane group from LDS (no split-k shuffles).
__global__ __launch_bounds__(256) void gat_agg32_fin_kernel(
    const int* __restrict__ rowp, const unsigned short* __restrict__ esrc,
    const __hip_bfloat16* __restrict__ feat, const float* __restrict__ als,
    const float* __restrict__ ald_arr, const float* __restrict__ bias,
    const float* __restrict__ M, const float* __restrict__ bf,
    float* __restrict__ out, int N) {
    __shared__ __align__(16) float Ms[16 * 36];    // row stride 36
    __shared__ float bfs[16];
    __shared__ __align__(16) float oL[4][32];
    int t = threadIdx.x;
    for (int i = t; i < 512; i += 256) Ms[(i >> 5) * 36 + (i & 31)] = M[i];
    if (t < 16) bfs[t] = bf[t];
    __syncthreads();
    const int lane = t & 63;
    const int wv = t >> 6;
    const int e = lane >> 3;             // edge slot 0..7
    const int c = lane & 7;              // head, channels 4c..4c+3
    int n = blockIdx.x * 4 + wv;
    if (n >= N) return;
    float aldv = ald_arr[n * 8 + c];
    int beg = rowp[n], end = rowp[n + 1];
    float dA = 0.f, dB = 0.f;
    float p0 = 0.f, p1 = 0.f, p2 = 0.f, p3 = 0.f;
    float q0 = 0.f, q1 = 0.f, q2 = 0.f, q3 = 0.f;
    const uint2* fp = (const uint2*)feat;    // 8 granules per row
    int i = beg;
    int s0, s1;
    bool has = (i + 16 <= end);
    if (has) { s0 = esrc[i + e]; s1 = esrc[i + 8 + e]; }
    while (has) {
        int t0 = s0, t1 = s1;
        i += 16;
        has = (i + 16 <= end);
        if (has) { s0 = esrc[i + e]; s1 = esrc[i + 8 + e]; }
        float e0 = als[t0 * 8 + c] + aldv;
        float e1 = als[t1 * 8 + c] + aldv;
        uint2 g0 = fp[t0 * 8 + c];
        uint2 g1 = fp[t1 * 8 + c];
        float w0 = __expf(lrelu(e0));
        float w1 = __expf(lrelu(e1));
        dA += w0; dB += w1;
        p0 += w0 * bfl2f(g0.x); p1 += w0 * bfh2f(g0.x);
        p2 += w0 * bfl2f(g0.y); p3 += w0 * bfh2f(g0.y);
        q0 += w1 * bfl2f(g1.x); q1 += w1 * bfh2f(g1.x);
        q2 += w1 * bfl2f(g1.y); q3 += w1 * bfh2f(g1.y);
    }
    for (; i < end; i += 8) {            // masked tail, 8 at a time
        int rem = end - i;
        int ee = (e < rem) ? e : rem - 1;
        int s = esrc[i + ee];
        float ev = als[s * 8 + c] + aldv;
        uint2 g = fp[s * 8 + c];
        float w = (e < rem) ? __expf(lrelu(ev)) : 0.f;
        dA += w;
        p0 += w * bfl2f(g.x); p1 += w * bfh2f(g.x);
        p2 += w * bfl2f(g.y); p3 += w * bfh2f(g.y);
    }
    float d = dA + dB;
    p0 += q0; p1 += q1; p2 += q2; p3 += q3;
    d  += __shfl_xor(d, 8);  d  += __shfl_xor(d, 16);  d  += __shfl_xor(d, 32);
    p0 += __shfl_xor(p0, 8); p0 += __shfl_xor(p0, 16); p0 += __shfl_xor(p0, 32);
    p1 += __shfl_xor(p1, 8); p1 += __shfl_xor(p1, 16); p1 += __shfl_xor(p1, 32);
    p2 += __shfl_xor(p2, 8); p2 += __shfl_xor(p2, 16); p2 += __shfl_xor(p2, 32);
    p3 += __shfl_xor(p3, 8); p3 += __shfl_xor(p3, 16); p3 += __shfl_xor(p3, 32);
    float inv = 1.f / (d + 1e-16f);
    float4 bv = ((const float4*)bias)[c];
    float o0 = elu(p0 * inv + bv.x);
    float o1 = elu(p1 * inv + bv.y);
    float o2 = elu(p2 * inv + bv.z);
    float o3 = elu(p3 * inv + bv.w);
    if (lane < 8) *(float4*)&oL[wv][c * 4] = make_float4(o0, o1, o2, o3);
    // final: logits[j] = sum_k M[j][k]*o[k] + bf[j]; each 16-lane group
    // computes all 16 logits redundantly (broadcast LDS reads, no shuffles)
    const int j = lane & 15;
    const float* orow = oL[wv];
    const float* mrow = &Ms[j * 36];
    float a0 = 0.f, a1 = 0.f, a2 = 0.f, a3 = 0.f;
#pragma unroll
    for (int g = 0; g < 8; ++g) {
        float4 ov = *(const float4*)&orow[g * 4];
        float4 mv = *(const float4*)&mrow[g * 4];
        a0 += ov.x * mv.x; a1 += ov.y * mv.y;
        a2 += ov.z * mv.z; a3 += ov.w * mv.w;
    }
    float logit = (a0 + a1) + (a2 + a3) + bfs[j];
    float mx = logit;
    mx = fmaxf(mx, __shfl_xor(mx, 1));
    mx = fmaxf(mx, __shfl_xor(mx, 2));
    mx = fmaxf(mx, __shfl_xor(mx, 4));
    mx = fmaxf(mx, __shfl_xor(mx, 8));
    float ex = __expf(logit - mx);
    float se = ex;
    se += __shfl_xor(se, 1);
    se += __shfl_xor(se, 2);
    se += __shfl_xor(se, 4);
    se += __shfl_xor(se, 8);
    float res = logit - (mx + __logf(se));
    if (lane < 16) out[(size_t)n * 16 + j] = res;
}

// ---------------- fold ----------------
__global__ __launch_bounds__(256) void fold_kernel(
    const float* __restrict__ in_proj_w, const float* __restrict__ in_proj_b,
    const float* __restrict__ out_proj_w, const float* __restrict__ out_proj_b,
    const float* __restrict__ fc_w, const float* __restrict__ fc_b,
    float* __restrict__ M, float* __restrict__ bf) {
    __shared__ float Wvo[32 * 32];
    __shared__ float bvo[32];
    const float* Wv = in_proj_w + 64 * 32;
    const float* bv = in_proj_b + 64;
    int t = threadIdx.x;
    for (int idx = t; idx < 1024; idx += 256) {
        int i = idx >> 5, j = idx & 31;
        float s = 0.f;
        for (int k = 0; k < 32; ++k) s += out_proj_w[i * 32 + k] * Wv[k * 32 + j];
        Wvo[idx] = s;
    }
    if (t < 32) {
        float s = 0.f;
        for (int k = 0; k < 32; ++k) s += out_proj_w[t * 32 + k] * bv[k];
        bvo[t] = s + out_proj_b[t];
    }
    __syncthreads();
    for (int idx = t; idx < 16 * 32; idx += 256) {
        int c = idx >> 5, j = idx & 31;
        float s = 0.f;
        for (int i = 0; i < 32; ++i) s += fc_w[c * 32 + i] * Wvo[i * 32 + j];
        M[idx] = s;
    }
    if (t < 16) {
        float s = 0.f;
        for (int i = 0; i < 32; ++i) s += fc_w[t * 32 + i] * bvo[i];
        bf[t] = s + fc_b[t];
    }
}

extern "C" void kernel_launch(void* const* d_in, const int* in_sizes, int n_in,
                              void* d_out, int out_size, void* d_ws, size_t ws_size,
                              hipStream_t stream) {
    const float* x   = (const float*)d_in[0];
    const int*   ei  = (const int*)d_in[1];
    const float* W1  = (const float*)d_in[2];
    const float* a1s = (const float*)d_in[3];
    const float* a1d = (const float*)d_in[4];
    const float* b1  = (const float*)d_in[5];
    const float* W2  = (const float*)d_in[6];
    const float* a2s = (const float*)d_in[7];
    const float* a2d = (const float*)d_in[8];
    const float* b2  = (const float*)d_in[9];
    const float* ipw = (const float*)d_in[10];
    const float* ipb = (const float*)d_in[11];
    const float* opw = (const float*)d_in[12];
    const float* opb = (const float*)d_in[13];
    const float* fcw = (const float*)d_in[14];
    const float* fcb = (const float*)d_in[15];
    float* out = (float*)d_out;

    int N = in_sizes[0] / 128;
    int E = in_sizes[1] / 2;
    int Et = E + N;
    int NB = (N + BMASK) >> BSHIFT;
    int NTILES = (Et + TILE - 1) / TILE;

    char* ws = (char*)d_ws;
    size_t off = 0;
    auto alloc = [&](size_t bytes) -> void* {
        void* p = ws + off;
        off += bytes;
        off = (off + 255) & ~(size_t)255;
        return p;
    };
    int*   bcount = (int*)alloc(MAXNB * 4);
    int*   bbase  = (int*)alloc(MAXNB * 4);
    int*   gcur   = (int*)alloc(MAXNB * 4);
    unsigned int*   rec  = (unsigned int*)alloc((size_t)Et * 4);
    int*   rowp   = (int*)alloc((size_t)(N + 1) * 4);
    unsigned short* esrc = (unsigned short*)alloc((size_t)Et * 2);
    __hip_bfloat16* h1 = (__hip_bfloat16*)alloc((size_t)N * 64 * 2);
    float* al1s  = (float*)alloc((size_t)N * 8 * 4);
    float* al1d  = (float*)alloc((size_t)N * 8 * 4);
    __hip_bfloat16* h2 = (__hip_bfloat16*)alloc((size_t)N * 32 * 2);
    float* al2s  = (float*)alloc((size_t)N * 8 * 4);
    float* al2d  = (float*)alloc((size_t)N * 8 * 4);
    float* Mf    = (float*)alloc(512 * 4);
    float* bff   = (float*)alloc(16 * 4);
    (void)ws_size; (void)n_in; (void)out_size;

    hipMemsetAsync(bcount, 0, MAXNB * 4, stream);
    bin_count_kernel<<<NTILES, 256, 0, stream>>>(ei, E, Et, NB, bcount);
    bucket_scan_kernel<<<1, 512, 0, stream>>>(bcount, bbase, gcur, NB);
    bin_scatter_kernel<<<NTILES, 256, 0, stream>>>(ei, E, Et, NB, gcur, rec);
    csr_finalize_kernel<<<NB, 256, 0, stream>>>(rec, bcount, bbase, rowp, esrc, N, Et);

    gemm1_mfma_kernel<<<(N + 63) / 64, 256, 0, stream>>>(x, W1, a1s, a1d, h1, al1s, al1d, N);
    fold_kernel<<<1, 256, 0, stream>>>(ipw, ipb, opw, opb, fcw, fcb, Mf, bff);
    gat_agg64_g2_kernel<<<(N + 3) / 4, 256, 0, stream>>>(
        rowp, esrc, h1, al1s, al1d, b1, W2, a2s, a2d, h2, al2s, al2d, N);
    gat_agg32_fin_kernel<<<(N + 3) / 4, 256, 0, stream>>>(
        rowp, esrc, h2, al2s, al2d, b2, Mf, bff, out, N);
}